// Round 2
// baseline (446.858 us; speedup 1.0000x reference)
//
#include <hip/hip_runtime.h>
#include <math.h>

#define NPOS 32768   // H*W*Z = 64*64*8
#define CCH 128

// ---------------- LN1: transpose (C,N)->(N,C) + layernorm over C ----------------
__global__ __launch_bounds__(256) void ln1_transpose_kernel(
    const float* __restrict__ x, const float* __restrict__ g,
    const float* __restrict__ b, float* __restrict__ out)
{
    __shared__ float tile[128][65];
    __shared__ float red[2][64][4];
    __shared__ float smu[64], srs[64];
    int n0 = blockIdx.x * 64;
    int tid = threadIdx.x;
    #pragma unroll
    for (int i = 0; i < 32; i++) {
        int idx = i * 256 + tid;
        int c = idx >> 6, nn = idx & 63;
        tile[c][nn] = x[(size_t)c * NPOS + n0 + nn];
    }
    __syncthreads();
    {
        int p = tid >> 2, s = tid & 3;
        float sum = 0.f, ssq = 0.f;
        #pragma unroll
        for (int i = 0; i < 32; i++) {
            float v = tile[s * 32 + i][p];
            sum += v; ssq += v * v;
        }
        red[0][p][s] = sum; red[1][p][s] = ssq;
    }
    __syncthreads();
    if (tid < 64) {
        float s = red[0][tid][0] + red[0][tid][1] + red[0][tid][2] + red[0][tid][3];
        float q = red[1][tid][0] + red[1][tid][1] + red[1][tid][2] + red[1][tid][3];
        float mu = s * (1.f / 128.f);
        float var = q * (1.f / 128.f) - mu * mu;
        smu[tid] = mu;
        srs[tid] = rsqrtf(var + 1e-5f);
    }
    __syncthreads();
    #pragma unroll
    for (int i = 0; i < 32; i++) {
        int idx = i * 256 + tid;
        int nn = idx >> 7, c = idx & 127;
        out[(size_t)(n0 + nn) * 128 + c] = (tile[c][nn] - smu[nn]) * srs[nn] * g[c] + b[c];
    }
}

// ---------------- generic fp32 GEMM: out[N][M] = A[N][K] @ B[K][M] + bias ----------------
// MODE 0: + bias
// MODE 1: + bias + x_transposed (aux0 is [C][N], adds aux0[c*N+r])
// MODE 2: gelu(+bias)
// MODE 3: final: v = acc + bias[c] + aux1[r*128+c] (x1) + aux0[c*N+r] (x); write transposed out[c*N+r]
__device__ __forceinline__ float gelu_f(float v) {
    float t = tanhf(0.7978845608028654f * (v + 0.044715f * v * v * v));
    return 0.5f * v * (1.f + t);
}

template<int MODE>
__global__ __launch_bounds__(256) void gemm_kernel(
    const float* __restrict__ A, const float* __restrict__ B,
    const float* __restrict__ bias, float* __restrict__ out,
    const float* __restrict__ aux0, const float* __restrict__ aux1,
    int N, int K, int M)
{
    __shared__ float As[64][33];
    __shared__ float Bs[32][65];
    int tid = threadIdx.x;
    int row0 = blockIdx.x * 64;
    int col0 = blockIdx.y * 64;
    int ty = tid >> 4, tx = tid & 15;
    float acc[4][4] = {};
    int alr = tid >> 3, alc = (tid & 7) << 2;
    int blr = tid >> 4, blc = (tid & 15) << 2;
    for (int k0 = 0; k0 < K; k0 += 32) {
        #pragma unroll
        for (int i = 0; i < 2; i++) {
            float4 av = *(const float4*)&A[(size_t)(row0 + alr + i * 32) * K + k0 + alc];
            As[alr + i * 32][alc + 0] = av.x;
            As[alr + i * 32][alc + 1] = av.y;
            As[alr + i * 32][alc + 2] = av.z;
            As[alr + i * 32][alc + 3] = av.w;
        }
        #pragma unroll
        for (int i = 0; i < 2; i++) {
            float4 bv = *(const float4*)&B[(size_t)(k0 + blr + i * 16) * M + col0 + blc];
            Bs[blr + i * 16][blc + 0] = bv.x;
            Bs[blr + i * 16][blc + 1] = bv.y;
            Bs[blr + i * 16][blc + 2] = bv.z;
            Bs[blr + i * 16][blc + 3] = bv.w;
        }
        __syncthreads();
        #pragma unroll
        for (int kk = 0; kk < 32; kk++) {
            float a[4], bb[4];
            #pragma unroll
            for (int i = 0; i < 4; i++) a[i] = As[ty * 4 + i][kk];
            #pragma unroll
            for (int j = 0; j < 4; j++) bb[j] = Bs[kk][tx * 4 + j];
            #pragma unroll
            for (int i = 0; i < 4; i++)
                #pragma unroll
                for (int j = 0; j < 4; j++)
                    acc[i][j] += a[i] * bb[j];
        }
        __syncthreads();
    }
    #pragma unroll
    for (int i = 0; i < 4; i++) {
        int r = row0 + ty * 4 + i;
        #pragma unroll
        for (int j = 0; j < 4; j++) {
            int c = col0 + tx * 4 + j;
            float v = acc[i][j] + bias[c];
            if (MODE == 1) v += aux0[(size_t)c * N + r];
            if (MODE == 2) v = gelu_f(v);
            if (MODE == 3) {
                v += aux1[(size_t)r * 128 + c] + aux0[(size_t)c * N + r];
                out[(size_t)c * N + r] = v;
            } else {
                out[(size_t)r * M + c] = v;
            }
        }
    }
}

// ---------------- neighborhood attention: one block per position ----------------
__global__ __launch_bounds__(256) void attn_kernel(
    const float* __restrict__ qkv,  // [N][384]  (q|k|v)
    const float* __restrict__ rpb,  // [8][5][5][5]
    float* __restrict__ out)        // [N][128]
{
    int n = blockIdx.x;
    int z = n & 7, w = (n >> 3) & 63, h = n >> 9;
    __shared__ float sq[128];
    __shared__ int nb[27];
    __shared__ int bofs[27];
    __shared__ float sc[8][28];
    int tid = threadIdx.x;
    if (tid < 128) sq[tid] = qkv[(size_t)n * 384 + tid] * 0.25f;  // hd^-0.5 = 1/4
    if (tid < 27) {
        int a = tid / 9, bb = (tid / 3) % 3, c = tid % 3;
        int sh = min(max(h - 1, 0), 64 - 3);
        int sw = min(max(w - 1, 0), 64 - 3);
        int sz = min(max(z - 1, 0), 8 - 3);
        int ih = sh + a, iw = sw + bb, iz = sz + c;
        nb[tid] = (ih << 9) + (iw << 3) + iz;
        int rh = ih - h + 2, rw = iw - w + 2, rz = iz - z + 2;
        bofs[tid] = rh * 25 + rw * 5 + rz;
    }
    __syncthreads();
    if (tid < 216) {
        int head = tid / 27, m = tid % 27;
        const float* kp = qkv + (size_t)nb[m] * 384 + 128 + head * 16;
        float s = 0.f;
        #pragma unroll
        for (int e = 0; e < 16; e++) s += sq[head * 16 + e] * kp[e];
        sc[head][m] = s + rpb[head * 125 + bofs[m]];
    }
    __syncthreads();
    if (tid < 8) {
        float mx = -1e30f;
        for (int m = 0; m < 27; m++) mx = fmaxf(mx, sc[tid][m]);
        float sum = 0.f;
        for (int m = 0; m < 27; m++) { float e = expf(sc[tid][m] - mx); sc[tid][m] = e; sum += e; }
        float inv = 1.f / sum;
        for (int m = 0; m < 27; m++) sc[tid][m] *= inv;
    }
    __syncthreads();
    if (tid < 128) {
        int head = tid >> 4, e = tid & 15;
        float acc = 0.f;
        #pragma unroll
        for (int m = 0; m < 27; m++)
            acc += sc[head][m] * qkv[(size_t)nb[m] * 384 + 256 + head * 16 + e];
        out[(size_t)n * 128 + tid] = acc;
    }
}

// ---------------- LN2: rows of 128, one wave per row ----------------
__global__ __launch_bounds__(256) void ln_rows_kernel(
    const float* __restrict__ in, const float* __restrict__ g,
    const float* __restrict__ b, float* __restrict__ out)
{
    int wid = (blockIdx.x * 256 + threadIdx.x) >> 6;
    int lane = threadIdx.x & 63;
    if (wid >= NPOS) return;
    const float* row = in + (size_t)wid * 128;
    float v0 = row[lane], v1 = row[lane + 64];
    float s = v0 + v1, ss = v0 * v0 + v1 * v1;
    #pragma unroll
    for (int o = 32; o > 0; o >>= 1) { s += __shfl_down(s, o); ss += __shfl_down(ss, o); }
    s = __shfl(s, 0); ss = __shfl(ss, 0);
    float mu = s * (1.f / 128.f);
    float var = ss * (1.f / 128.f) - mu * mu;
    float rs = rsqrtf(var + 1e-5f);
    out[(size_t)wid * 128 + lane] = (v0 - mu) * rs * g[lane] + b[lane];
    out[(size_t)wid * 128 + lane + 64] = (v1 - mu) * rs * g[lane + 64] + b[lane + 64];
}

// ---------------- 2x2x2 maxpool over (H,W,Z) ----------------
__global__ __launch_bounds__(256) void pool_kernel(
    const float* __restrict__ skip, float* __restrict__ pooled)
{
    int t = blockIdx.x * 256 + threadIdx.x;
    if (t >= 128 * 32 * 32 * 4) return;
    int oz = t & 3, ow = (t >> 2) & 31, oh = (t >> 7) & 31, c = t >> 12;
    const float* base = skip + (size_t)c * 32768 + (oh * 2) * 512 + (ow * 2) * 8 + oz * 2;
    float m = -INFINITY;
    #pragma unroll
    for (int dh = 0; dh < 2; dh++)
        #pragma unroll
        for (int dw = 0; dw < 2; dw++)
            #pragma unroll
            for (int dz = 0; dz < 2; dz++)
                m = fmaxf(m, base[dh * 512 + dw * 8 + dz]);
    pooled[t] = m;
}

extern "C" void kernel_launch(void* const* d_in, const int* in_sizes, int n_in,
                              void* d_out, int out_size, void* d_ws, size_t ws_size,
                              hipStream_t stream) {
    const float* x      = (const float*)d_in[0];
    const float* ln1_g  = (const float*)d_in[1];
    const float* ln1_b  = (const float*)d_in[2];
    const float* qkv_w  = (const float*)d_in[3];
    const float* qkv_b  = (const float*)d_in[4];
    const float* proj_w = (const float*)d_in[5];
    const float* proj_b = (const float*)d_in[6];
    const float* rpb    = (const float*)d_in[7];
    const float* ln2_g  = (const float*)d_in[8];
    const float* ln2_b  = (const float*)d_in[9];
    const float* w1     = (const float*)d_in[10];
    const float* b1     = (const float*)d_in[11];
    const float* w2     = (const float*)d_in[12];
    const float* b2     = (const float*)d_in[13];

    const int N = NPOS;
    float* ws = (float*)d_ws;
    float* buf0 = ws;                     // N*128: xn -> attn_out -> ln2out
    float* buf1 = buf0 + (size_t)N * 128; // N*512: qkv (uses 384) -> mlp hidden (512)
    float* buf2 = buf1 + (size_t)N * 512; // N*128: x1

    float* out_pooled = (float*)d_out;
    float* out_skip   = (float*)d_out + 524288;

    // 1. transpose + LN1
    ln1_transpose_kernel<<<N / 64, 256, 0, stream>>>(x, ln1_g, ln1_b, buf0);

    // 2. QKV GEMM: [N,128] @ [128,384]
    {
        dim3 g(N / 64, 384 / 64);
        gemm_kernel<0><<<g, 256, 0, stream>>>(buf0, qkv_w, qkv_b, buf1, nullptr, nullptr, N, 128, 384);
    }

    // 3. neighborhood attention -> buf0
    attn_kernel<<<N, 256, 0, stream>>>(buf1, rpb, buf0);

    // 4. proj GEMM + residual(x^T): x1 = attn_out @ proj_w + proj_b + xp
    {
        dim3 g(N / 64, 128 / 64);
        gemm_kernel<1><<<g, 256, 0, stream>>>(buf0, proj_w, proj_b, buf2, x, nullptr, N, 128, 128);
    }

    // 5. LN2 -> buf0
    ln_rows_kernel<<<N / 4, 256, 0, stream>>>(buf2, ln2_g, ln2_b, buf0);

    // 6. MLP1 + gelu: [N,128] @ [128,512] -> buf1
    {
        dim3 g(N / 64, 512 / 64);
        gemm_kernel<2><<<g, 256, 0, stream>>>(buf0, w1, b1, buf1, nullptr, nullptr, N, 128, 512);
    }

    // 7. MLP2 + bias + x1 + x -> skip (transposed write into d_out)
    {
        dim3 g(N / 64, 128 / 64);
        gemm_kernel<3><<<g, 256, 0, stream>>>(buf1, w2, b2, out_skip, x, buf2, N, 512, 128);
    }

    // 8. maxpool -> pooled
    pool_kernel<<<(524288 + 255) / 256, 256, 0, stream>>>(out_skip, out_pooled);
}

// Round 3
// 251.586 us; speedup vs baseline: 1.7762x; 1.7762x over previous
//
#include <hip/hip_runtime.h>
#include <hip/hip_bf16.h>
#include <math.h>

#define NPOS 32768   // H*W*Z = 64*64*8

typedef __hip_bfloat16 bf16;
typedef __attribute__((ext_vector_type(8))) short bf16x8;
typedef __attribute__((ext_vector_type(4))) float f32x4;

// ---------------- weight transpose + fp32->bf16: src[K][M] -> dst[M][K] ----------------
__global__ __launch_bounds__(256) void wt_transpose_kernel(
    const float* __restrict__ src, bf16* __restrict__ dst, int K, int M)
{
    __shared__ float tile[32][33];
    int m0 = blockIdx.x * 32, k0 = blockIdx.y * 32;
    int tx = threadIdx.x & 31, ty = threadIdx.x >> 5;  // ty 0..7
    #pragma unroll
    for (int i = 0; i < 4; i++)
        tile[ty + i * 8][tx] = src[(size_t)(k0 + ty + i * 8) * M + m0 + tx];
    __syncthreads();
    #pragma unroll
    for (int i = 0; i < 4; i++)
        dst[(size_t)(m0 + ty + i * 8) * K + k0 + tx] = __float2bfloat16(tile[tx][ty + i * 8]);
}

// ---------------- LN1: transpose (C,N)->(N,C) + layernorm over C, out bf16 ----------------
__global__ __launch_bounds__(256) void ln1_transpose_kernel(
    const float* __restrict__ x, const float* __restrict__ g,
    const float* __restrict__ b, bf16* __restrict__ out)
{
    __shared__ float tile[128][65];
    __shared__ float red[2][64][4];
    __shared__ float smu[64], srs[64];
    int n0 = blockIdx.x * 64;
    int tid = threadIdx.x;
    #pragma unroll
    for (int i = 0; i < 32; i++) {
        int idx = i * 256 + tid;
        int c = idx >> 6, nn = idx & 63;
        tile[c][nn] = x[(size_t)c * NPOS + n0 + nn];
    }
    __syncthreads();
    {
        int p = tid >> 2, s = tid & 3;
        float sum = 0.f, ssq = 0.f;
        #pragma unroll
        for (int i = 0; i < 32; i++) {
            float v = tile[s * 32 + i][p];
            sum += v; ssq += v * v;
        }
        red[0][p][s] = sum; red[1][p][s] = ssq;
    }
    __syncthreads();
    if (tid < 64) {
        float s = red[0][tid][0] + red[0][tid][1] + red[0][tid][2] + red[0][tid][3];
        float q = red[1][tid][0] + red[1][tid][1] + red[1][tid][2] + red[1][tid][3];
        float mu = s * (1.f / 128.f);
        float var = q * (1.f / 128.f) - mu * mu;
        smu[tid] = mu;
        srs[tid] = rsqrtf(var + 1e-5f);
    }
    __syncthreads();
    #pragma unroll
    for (int i = 0; i < 32; i++) {
        int idx = i * 256 + tid;
        int nn = idx >> 7, c = idx & 127;
        out[(size_t)(n0 + nn) * 128 + c] =
            __float2bfloat16((tile[c][nn] - smu[nn]) * srs[nn] * g[c] + b[c]);
    }
}

// ---------------- bf16 MFMA GEMM: out[N][M] = A[N][K] @ Bt[M][K]^T + bias ----------------
// MODE 0: write bf16, +bias                       (QKV)
// MODE 1: write fp32 [N][128], +bias + aux0[c*N+r] (proj: x1 = .. + xp)
// MODE 2: write bf16, gelu(+bias)                 (MLP1)
// MODE 3: write fp32 TRANSPOSED out[c*N+r], +bias + aux1[r*128+c] + aux0[c*N+r] (MLP2->skip)
__device__ __forceinline__ float gelu_f(float v) {
    float t = tanhf(0.7978845608028654f * (v + 0.044715f * v * v * v));
    return 0.5f * v * (1.f + t);
}

template<int MODE>
__global__ __launch_bounds__(256) void gemm_mfma_kernel(
    const bf16* __restrict__ A, const bf16* __restrict__ Bt,
    const float* __restrict__ bias, void* __restrict__ outv,
    const float* __restrict__ aux0, const float* __restrict__ aux1,
    int N, int K, int M)
{
    __shared__ __align__(16) bf16 As[128][72];   // +8 pad: 144B row stride (9x16B)
    __shared__ __align__(16) bf16 Bs[128][72];
    int tid = threadIdx.x;
    int row0 = blockIdx.x * 128;
    int col0 = blockIdx.y * 128;
    int lane = tid & 63, wid = tid >> 6;
    int wr = wid >> 1, wc = wid & 1;          // wave tile: 64x64 at (wr,wc)
    int lr = lane & 15, kg = lane >> 4;       // fragment row/col + k-group

    f32x4 acc[4][4] = {};

    for (int k0 = 0; k0 < K; k0 += 64) {
        // stage A,B tiles: 128 rows x 64 cols each; 1024 16B-chunks per tile
        bf16x8 ra[4], rb[4];
        #pragma unroll
        for (int i = 0; i < 4; i++) {
            int c = tid + i * 256;
            int r = c >> 3, c8 = c & 7;
            ra[i] = *(const bf16x8*)(A  + (size_t)(row0 + r) * K + k0 + c8 * 8);
            rb[i] = *(const bf16x8*)(Bt + (size_t)(col0 + r) * K + k0 + c8 * 8);
        }
        if (k0 > 0) __syncthreads();   // previous compute must finish before overwrite
        #pragma unroll
        for (int i = 0; i < 4; i++) {
            int c = tid + i * 256;
            int r = c >> 3, c8 = c & 7;
            *(bf16x8*)&As[r][c8 * 8] = ra[i];
            *(bf16x8*)&Bs[r][c8 * 8] = rb[i];
        }
        __syncthreads();
        #pragma unroll
        for (int ks = 0; ks < 2; ks++) {
            bf16x8 af[4], bf_[4];
            #pragma unroll
            for (int m = 0; m < 4; m++)
                af[m] = *(const bf16x8*)&As[wr * 64 + m * 16 + lr][ks * 32 + kg * 8];
            #pragma unroll
            for (int n = 0; n < 4; n++)
                bf_[n] = *(const bf16x8*)&Bs[wc * 64 + n * 16 + lr][ks * 32 + kg * 8];
            #pragma unroll
            for (int m = 0; m < 4; m++)
                #pragma unroll
                for (int n = 0; n < 4; n++)
                    acc[m][n] = __builtin_amdgcn_mfma_f32_16x16x32_bf16(af[m], bf_[n], acc[m][n], 0, 0, 0);
        }
    }

    // epilogue
    #pragma unroll
    for (int m = 0; m < 4; m++) {
        #pragma unroll
        for (int n = 0; n < 4; n++) {
            int c = col0 + wc * 64 + n * 16 + lr;
            float bv = bias[c];
            #pragma unroll
            for (int j = 0; j < 4; j++) {
                int r = row0 + wr * 64 + m * 16 + kg * 4 + j;
                float v = acc[m][n][j] + bv;
                if (MODE == 0) {
                    ((bf16*)outv)[(size_t)r * M + c] = __float2bfloat16(v);
                } else if (MODE == 1) {
                    v += aux0[(size_t)c * N + r];
                    ((float*)outv)[(size_t)r * M + c] = v;
                } else if (MODE == 2) {
                    ((bf16*)outv)[(size_t)r * M + c] = __float2bfloat16(gelu_f(v));
                } else {
                    v += aux1[(size_t)r * 128 + c] + aux0[(size_t)c * N + r];
                    ((float*)outv)[(size_t)c * N + r] = v;
                }
            }
        }
    }
}

// ---------------- neighborhood attention (bf16 qkv): one block per position ----------------
__global__ __launch_bounds__(256) void attn_kernel(
    const bf16* __restrict__ qkv,   // [N][384]  (q|k|v)
    const float* __restrict__ rpb,  // [8][5][5][5]
    bf16* __restrict__ out)         // [N][128]
{
    int n = blockIdx.x;
    int z = n & 7, w = (n >> 3) & 63, h = n >> 9;
    __shared__ float sq[128];
    __shared__ int nb[27];
    __shared__ int bofs[27];
    __shared__ float sc[8][28];
    int tid = threadIdx.x;
    if (tid < 128) sq[tid] = __bfloat162float(qkv[(size_t)n * 384 + tid]) * 0.25f;
    if (tid < 27) {
        int a = tid / 9, bb = (tid / 3) % 3, c = tid % 3;
        int sh = min(max(h - 1, 0), 64 - 3);
        int sw = min(max(w - 1, 0), 64 - 3);
        int sz = min(max(z - 1, 0), 8 - 3);
        int ih = sh + a, iw = sw + bb, iz = sz + c;
        nb[tid] = (ih << 9) + (iw << 3) + iz;
        int rh = ih - h + 2, rw = iw - w + 2, rz = iz - z + 2;
        bofs[tid] = rh * 25 + rw * 5 + rz;
    }
    __syncthreads();
    if (tid < 216) {
        int head = tid / 27, m = tid % 27;
        const bf16* kp = qkv + (size_t)nb[m] * 384 + 128 + head * 16;
        float s = 0.f;
        #pragma unroll
        for (int e = 0; e < 16; e++) s += sq[head * 16 + e] * __bfloat162float(kp[e]);
        sc[head][m] = s + rpb[head * 125 + bofs[m]];
    }
    __syncthreads();
    if (tid < 8) {
        float mx = -1e30f;
        for (int m = 0; m < 27; m++) mx = fmaxf(mx, sc[tid][m]);
        float sum = 0.f;
        for (int m = 0; m < 27; m++) { float e = expf(sc[tid][m] - mx); sc[tid][m] = e; sum += e; }
        float inv = 1.f / sum;
        for (int m = 0; m < 27; m++) sc[tid][m] *= inv;
    }
    __syncthreads();
    if (tid < 128) {
        int head = tid >> 4, e = tid & 15;
        float acc = 0.f;
        #pragma unroll
        for (int m = 0; m < 27; m++)
            acc += sc[head][m] * __bfloat162float(qkv[(size_t)nb[m] * 384 + 256 + head * 16 + e]);
        out[(size_t)n * 128 + tid] = __float2bfloat16(acc);
    }
}

// ---------------- LN2: rows of 128 fp32 -> bf16, one wave per row ----------------
__global__ __launch_bounds__(256) void ln_rows_kernel(
    const float* __restrict__ in, const float* __restrict__ g,
    const float* __restrict__ b, bf16* __restrict__ out)
{
    int wid = (blockIdx.x * 256 + threadIdx.x) >> 6;
    int lane = threadIdx.x & 63;
    if (wid >= NPOS) return;
    const float* row = in + (size_t)wid * 128;
    float v0 = row[lane], v1 = row[lane + 64];
    float s = v0 + v1, ss = v0 * v0 + v1 * v1;
    #pragma unroll
    for (int o = 32; o > 0; o >>= 1) { s += __shfl_down(s, o); ss += __shfl_down(ss, o); }
    s = __shfl(s, 0); ss = __shfl(ss, 0);
    float mu = s * (1.f / 128.f);
    float var = ss * (1.f / 128.f) - mu * mu;
    float rs = rsqrtf(var + 1e-5f);
    out[(size_t)wid * 128 + lane]      = __float2bfloat16((v0 - mu) * rs * g[lane] + b[lane]);
    out[(size_t)wid * 128 + lane + 64] = __float2bfloat16((v1 - mu) * rs * g[lane + 64] + b[lane + 64]);
}

// ---------------- 2x2x2 maxpool over (H,W,Z) ----------------
__global__ __launch_bounds__(256) void pool_kernel(
    const float* __restrict__ skip, float* __restrict__ pooled)
{
    int t = blockIdx.x * 256 + threadIdx.x;
    if (t >= 128 * 32 * 32 * 4) return;
    int oz = t & 3, ow = (t >> 2) & 31, oh = (t >> 7) & 31, c = t >> 12;
    const float* base = skip + (size_t)c * 32768 + (oh * 2) * 512 + (ow * 2) * 8 + oz * 2;
    float m = -INFINITY;
    #pragma unroll
    for (int dh = 0; dh < 2; dh++)
        #pragma unroll
        for (int dw = 0; dw < 2; dw++)
            #pragma unroll
            for (int dz = 0; dz < 2; dz++)
                m = fmaxf(m, base[dh * 512 + dw * 8 + dz]);
    pooled[t] = m;
}

extern "C" void kernel_launch(void* const* d_in, const int* in_sizes, int n_in,
                              void* d_out, int out_size, void* d_ws, size_t ws_size,
                              hipStream_t stream) {
    const float* x      = (const float*)d_in[0];
    const float* ln1_g  = (const float*)d_in[1];
    const float* ln1_b  = (const float*)d_in[2];
    const float* qkv_w  = (const float*)d_in[3];
    const float* qkv_b  = (const float*)d_in[4];
    const float* proj_w = (const float*)d_in[5];
    const float* proj_b = (const float*)d_in[6];
    const float* rpb    = (const float*)d_in[7];
    const float* ln2_g  = (const float*)d_in[8];
    const float* ln2_b  = (const float*)d_in[9];
    const float* w1     = (const float*)d_in[10];
    const float* b1     = (const float*)d_in[11];
    const float* w2     = (const float*)d_in[12];
    const float* b2     = (const float*)d_in[13];

    const int N = NPOS;
    char* wsc = (char*)d_ws;
    bf16*  buf0 = (bf16*)wsc;                               // N*128 bf16: xn -> attn_out -> ln2out
    bf16*  buf1 = (bf16*)(wsc + (size_t)N * 128 * 2);       // N*512 bf16: qkv(384) -> hidden(512)
    float* buf2 = (float*)(wsc + (size_t)N * 128 * 2 + (size_t)N * 512 * 2);  // N*128 f32: x1
    char*  wts  = wsc + (size_t)N * 128 * 2 + (size_t)N * 512 * 2 + (size_t)N * 128 * 4;
    bf16* wt_qkv  = (bf16*)wts;                 // [384][128]
    bf16* wt_proj = wt_qkv  + 384 * 128;        // [128][128]
    bf16* wt_w1   = wt_proj + 128 * 128;        // [512][128]
    bf16* wt_w2   = wt_w1   + 512 * 128;        // [128][512]

    float* out_pooled = (float*)d_out;
    float* out_skip   = (float*)d_out + 524288;

    // 0. weight transposes (fp32 [K][M] -> bf16 [M][K])
    wt_transpose_kernel<<<dim3(384 / 32, 128 / 32), 256, 0, stream>>>(qkv_w, wt_qkv, 128, 384);
    wt_transpose_kernel<<<dim3(128 / 32, 128 / 32), 256, 0, stream>>>(proj_w, wt_proj, 128, 128);
    wt_transpose_kernel<<<dim3(512 / 32, 128 / 32), 256, 0, stream>>>(w1, wt_w1, 128, 512);
    wt_transpose_kernel<<<dim3(128 / 32, 512 / 32), 256, 0, stream>>>(w2, wt_w2, 512, 128);

    // 1. transpose + LN1 -> bf16
    ln1_transpose_kernel<<<N / 64, 256, 0, stream>>>(x, ln1_g, ln1_b, buf0);

    // 2. QKV GEMM: [N,128] @ [128,384] -> bf16
    gemm_mfma_kernel<0><<<dim3(N / 128, 384 / 128), 256, 0, stream>>>(
        buf0, wt_qkv, qkv_b, buf1, nullptr, nullptr, N, 128, 384);

    // 3. neighborhood attention -> bf16
    attn_kernel<<<N, 256, 0, stream>>>(buf1, rpb, buf0);

    // 4. proj GEMM + residual(x^T): x1(f32) = attn_out @ proj_w + proj_b + xp
    gemm_mfma_kernel<1><<<dim3(N / 128, 1), 256, 0, stream>>>(
        buf0, wt_proj, proj_b, buf2, x, nullptr, N, 128, 128);

    // 5. LN2 -> bf16
    ln_rows_kernel<<<N / 4, 256, 0, stream>>>(buf2, ln2_g, ln2_b, buf0);

    // 6. MLP1 + gelu: [N,128] @ [128,512] -> bf16
    gemm_mfma_kernel<2><<<dim3(N / 128, 512 / 128), 256, 0, stream>>>(
        buf0, wt_w1, b1, buf1, nullptr, nullptr, N, 128, 512);

    // 7. MLP2 + bias + x1 + x -> skip (transposed fp32 write into d_out)
    gemm_mfma_kernel<3><<<dim3(N / 128, 1), 256, 0, stream>>>(
        buf1, wt_w2, b2, out_skip, x, buf2, N, 512, 128);

    // 8. maxpool -> pooled
    pool_kernel<<<(524288 + 255) / 256, 256, 0, stream>>>(out_skip, out_pooled);
}

// Round 4
// 207.442 us; speedup vs baseline: 2.1541x; 1.2128x over previous
//
#include <hip/hip_runtime.h>
#include <hip/hip_bf16.h>
#include <math.h>

#define NPOS 32768   // H*W*Z = 64*64*8

typedef __hip_bfloat16 bf16;
typedef __attribute__((ext_vector_type(8))) short bf16x8;
typedef __attribute__((ext_vector_type(4))) float f32x4;

__device__ __forceinline__ float bf2f(short s) {
    union { unsigned u; float f; } cv;
    cv.u = ((unsigned)(unsigned short)s) << 16;
    return cv.f;
}

// ---------------- weight transpose + fp32->bf16: src[K][M] -> dst[M][K] ----------------
__global__ __launch_bounds__(256) void wt_transpose_kernel(
    const float* __restrict__ src, bf16* __restrict__ dst, int K, int M)
{
    __shared__ float tile[32][33];
    int m0 = blockIdx.x * 32, k0 = blockIdx.y * 32;
    int tx = threadIdx.x & 31, ty = threadIdx.x >> 5;  // ty 0..7
    #pragma unroll
    for (int i = 0; i < 4; i++)
        tile[ty + i * 8][tx] = src[(size_t)(k0 + ty + i * 8) * M + m0 + tx];
    __syncthreads();
    #pragma unroll
    for (int i = 0; i < 4; i++)
        dst[(size_t)(m0 + ty + i * 8) * K + k0 + tx] = __float2bfloat16(tile[tx][ty + i * 8]);
}

// ---------------- LN1: transpose (C,N)->(N,C) + layernorm over C, out bf16 ----------------
__global__ __launch_bounds__(256) void ln1_transpose_kernel(
    const float* __restrict__ x, const float* __restrict__ g,
    const float* __restrict__ b, bf16* __restrict__ out)
{
    __shared__ float tile[128][65];
    __shared__ float red[2][64][4];
    __shared__ float smu[64], srs[64];
    int n0 = blockIdx.x * 64;
    int tid = threadIdx.x;
    #pragma unroll
    for (int i = 0; i < 32; i++) {
        int idx = i * 256 + tid;
        int c = idx >> 6, nn = idx & 63;
        tile[c][nn] = x[(size_t)c * NPOS + n0 + nn];
    }
    __syncthreads();
    {
        int p = tid >> 2, s = tid & 3;
        float sum = 0.f, ssq = 0.f;
        #pragma unroll
        for (int i = 0; i < 32; i++) {
            float v = tile[s * 32 + i][p];
            sum += v; ssq += v * v;
        }
        red[0][p][s] = sum; red[1][p][s] = ssq;
    }
    __syncthreads();
    if (tid < 64) {
        float s = red[0][tid][0] + red[0][tid][1] + red[0][tid][2] + red[0][tid][3];
        float q = red[1][tid][0] + red[1][tid][1] + red[1][tid][2] + red[1][tid][3];
        float mu = s * (1.f / 128.f);
        float var = q * (1.f / 128.f) - mu * mu;
        smu[tid] = mu;
        srs[tid] = rsqrtf(var + 1e-5f);
    }
    __syncthreads();
    #pragma unroll
    for (int i = 0; i < 32; i++) {
        int idx = i * 256 + tid;
        int nn = idx >> 7, c = idx & 127;
        out[(size_t)(n0 + nn) * 128 + c] =
            __float2bfloat16((tile[c][nn] - smu[nn]) * srs[nn] * g[c] + b[c]);
    }
}

// ---------------- bf16 MFMA GEMM: out[N][M] = A[N][K] @ Bt[M][K]^T + bias ----------------
__device__ __forceinline__ float gelu_f(float v) {
    float t = tanhf(0.7978845608028654f * (v + 0.044715f * v * v * v));
    return 0.5f * v * (1.f + t);
}

template<int MODE>
__global__ __launch_bounds__(256) void gemm_mfma_kernel(
    const bf16* __restrict__ A, const bf16* __restrict__ Bt,
    const float* __restrict__ bias, void* __restrict__ outv,
    const float* __restrict__ aux0, const float* __restrict__ aux1,
    int N, int K, int M)
{
    __shared__ __align__(16) bf16 As[128][72];   // +8 pad
    __shared__ __align__(16) bf16 Bs[128][72];
    int tid = threadIdx.x;
    int row0 = blockIdx.x * 128;
    int col0 = blockIdx.y * 128;
    int lane = tid & 63, wid = tid >> 6;
    int wr = wid >> 1, wc = wid & 1;
    int lr = lane & 15, kg = lane >> 4;

    f32x4 acc[4][4] = {};

    for (int k0 = 0; k0 < K; k0 += 64) {
        bf16x8 ra[4], rb[4];
        #pragma unroll
        for (int i = 0; i < 4; i++) {
            int c = tid + i * 256;
            int r = c >> 3, c8 = c & 7;
            ra[i] = *(const bf16x8*)(A  + (size_t)(row0 + r) * K + k0 + c8 * 8);
            rb[i] = *(const bf16x8*)(Bt + (size_t)(col0 + r) * K + k0 + c8 * 8);
        }
        if (k0 > 0) __syncthreads();
        #pragma unroll
        for (int i = 0; i < 4; i++) {
            int c = tid + i * 256;
            int r = c >> 3, c8 = c & 7;
            *(bf16x8*)&As[r][c8 * 8] = ra[i];
            *(bf16x8*)&Bs[r][c8 * 8] = rb[i];
        }
        __syncthreads();
        #pragma unroll
        for (int ks = 0; ks < 2; ks++) {
            bf16x8 af[4], bf_[4];
            #pragma unroll
            for (int m = 0; m < 4; m++)
                af[m] = *(const bf16x8*)&As[wr * 64 + m * 16 + lr][ks * 32 + kg * 8];
            #pragma unroll
            for (int n = 0; n < 4; n++)
                bf_[n] = *(const bf16x8*)&Bs[wc * 64 + n * 16 + lr][ks * 32 + kg * 8];
            #pragma unroll
            for (int m = 0; m < 4; m++)
                #pragma unroll
                for (int n = 0; n < 4; n++)
                    acc[m][n] = __builtin_amdgcn_mfma_f32_16x16x32_bf16(af[m], bf_[n], acc[m][n], 0, 0, 0);
        }
    }

    #pragma unroll
    for (int m = 0; m < 4; m++) {
        #pragma unroll
        for (int n = 0; n < 4; n++) {
            int c = col0 + wc * 64 + n * 16 + lr;
            float bv = bias[c];
            #pragma unroll
            for (int j = 0; j < 4; j++) {
                int r = row0 + wr * 64 + m * 16 + kg * 4 + j;
                float v = acc[m][n][j] + bv;
                if (MODE == 0) {
                    ((bf16*)outv)[(size_t)r * M + c] = __float2bfloat16(v);
                } else if (MODE == 1) {
                    v += aux0[(size_t)c * N + r];
                    ((float*)outv)[(size_t)r * M + c] = v;
                } else if (MODE == 2) {
                    ((bf16*)outv)[(size_t)r * M + c] = __float2bfloat16(gelu_f(v));
                } else {
                    v += aux1[(size_t)r * 128 + c] + aux0[(size_t)c * N + r];
                    ((float*)outv)[(size_t)c * N + r] = v;
                }
            }
        }
    }
}

// ---------------- neighborhood attention v2: 1 thread per (position, head) ----------------
// Block = 32 positions (1 h, 4 w, 8 z) x 8 heads. K/V bbox (3h x 6w x 8z = 144 pos)
// staged in LDS, rows padded to 136 bf16 (272B).
__global__ __launch_bounds__(256) void attn_kernel(
    const bf16* __restrict__ qkv,   // [N][384]  (q|k|v)
    const float* __restrict__ rpb,  // [8][5][5][5]
    bf16* __restrict__ out)         // [N][128]
{
    __shared__ __align__(16) bf16 klds[144 * 136];
    __shared__ __align__(16) bf16 vlds[144 * 136];
    int tid = threadIdx.x;
    int h  = blockIdx.x >> 4;
    int w0 = (blockIdx.x & 15) << 2;
    int n0 = (h << 9) + (w0 << 3);
    int bh = min(max(h - 1, 0), 61);
    int bw = min(max(w0 - 1, 0), 58);

    // stage K/V: 144 positions x (16+16) 16B-chunks = 4608 chunks, 18/thread
    #pragma unroll
    for (int i = 0; i < 18; i++) {
        int chunk = i * 256 + tid;
        int s = chunk >> 5;            // staged position 0..143
        int w32 = chunk & 31;
        int isv = w32 >> 4, c16 = w32 & 15;
        unsigned rc = (unsigned)(s >> 3);
        int z = s & 7;
        int r = rc / 6u, c = rc % 6u;
        int ns = ((bh + r) << 9) + ((bw + c) << 3) + z;
        bf16x8 val = *(const bf16x8*)(qkv + (size_t)ns * 384 + 128 + isv * 128 + c16 * 8);
        bf16* dst = (isv ? vlds : klds) + s * 136 + c16 * 8;
        *(bf16x8*)dst = val;
    }
    __syncthreads();

    int p = tid >> 3, head = tid & 7;
    int pw = p >> 3, z = p & 7;
    int w = w0 + pw;
    int n = n0 + p;

    // q fragment -> fp32 regs, pre-scaled by hd^-0.5 = 0.25
    float qf[16];
    {
        const bf16* qp = qkv + (size_t)n * 384 + head * 16;
        bf16x8 q0 = *(const bf16x8*)qp;
        bf16x8 q1 = *(const bf16x8*)(qp + 8);
        #pragma unroll
        for (int e = 0; e < 8; e++) {
            qf[e]     = bf2f(q0[e]) * 0.25f;
            qf[e + 8] = bf2f(q1[e]) * 0.25f;
        }
    }

    int sw = min(max(w - 1, 0), 61);
    int sz = min(max(z - 1, 0), 5);
    int cb = sw - bw;                 // 0..5 window col base in staged tile

    float sc[27];
    int   lp[27];
    float mx = -1e30f;
    int mi = 0;
    #pragma unroll
    for (int a = 0; a < 3; a++) {
        #pragma unroll
        for (int b = 0; b < 3; b++) {
            #pragma unroll
            for (int c = 0; c < 3; c++) {
                int lpos = ((a * 6 + cb + b) << 3) + sz + c;
                const bf16* kp = klds + lpos * 136 + head * 16;
                bf16x8 k0 = *(const bf16x8*)kp;
                bf16x8 k1 = *(const bf16x8*)(kp + 8);
                float s = 0.f;
                #pragma unroll
                for (int e = 0; e < 8; e++) s = fmaf(qf[e], bf2f(k0[e]), s);
                #pragma unroll
                for (int e = 0; e < 8; e++) s = fmaf(qf[e + 8], bf2f(k1[e]), s);
                s += rpb[head * 125 + (bh + a - h + 2) * 25 + (sw + b - w + 2) * 5 + (sz + c - z + 2)];
                sc[mi] = s;
                lp[mi] = lpos;
                mx = fmaxf(mx, s);
                mi++;
            }
        }
    }

    float sum = 0.f;
    #pragma unroll
    for (int m = 0; m < 27; m++) {
        float e = __expf(sc[m] - mx);
        sc[m] = e;
        sum += e;
    }
    float inv = 1.f / sum;

    float o[16] = {};
    #pragma unroll
    for (int m = 0; m < 27; m++) {
        const bf16* vp = vlds + lp[m] * 136 + head * 16;
        bf16x8 v0 = *(const bf16x8*)vp;
        bf16x8 v1 = *(const bf16x8*)(vp + 8);
        float pm = sc[m];
        #pragma unroll
        for (int e = 0; e < 8; e++) {
            o[e]     = fmaf(pm, bf2f(v0[e]), o[e]);
            o[e + 8] = fmaf(pm, bf2f(v1[e]), o[e + 8]);
        }
    }

    bf16* op = out + (size_t)n * 128 + head * 16;
    #pragma unroll
    for (int e = 0; e < 16; e++)
        op[e] = __float2bfloat16(o[e] * inv);
}

// ---------------- LN2: rows of 128 fp32 -> bf16, one wave per row ----------------
__global__ __launch_bounds__(256) void ln_rows_kernel(
    const float* __restrict__ in, const float* __restrict__ g,
    const float* __restrict__ b, bf16* __restrict__ out)
{
    int wid = (blockIdx.x * 256 + threadIdx.x) >> 6;
    int lane = threadIdx.x & 63;
    if (wid >= NPOS) return;
    const float* row = in + (size_t)wid * 128;
    float v0 = row[lane], v1 = row[lane + 64];
    float s = v0 + v1, ss = v0 * v0 + v1 * v1;
    #pragma unroll
    for (int o = 32; o > 0; o >>= 1) { s += __shfl_down(s, o); ss += __shfl_down(ss, o); }
    s = __shfl(s, 0); ss = __shfl(ss, 0);
    float mu = s * (1.f / 128.f);
    float var = ss * (1.f / 128.f) - mu * mu;
    float rs = rsqrtf(var + 1e-5f);
    out[(size_t)wid * 128 + lane]      = __float2bfloat16((v0 - mu) * rs * g[lane] + b[lane]);
    out[(size_t)wid * 128 + lane + 64] = __float2bfloat16((v1 - mu) * rs * g[lane + 64] + b[lane + 64]);
}

// ---------------- 2x2x2 maxpool over (H,W,Z) ----------------
__global__ __launch_bounds__(256) void pool_kernel(
    const float* __restrict__ skip, float* __restrict__ pooled)
{
    int t = blockIdx.x * 256 + threadIdx.x;
    if (t >= 128 * 32 * 32 * 4) return;
    int oz = t & 3, ow = (t >> 2) & 31, oh = (t >> 7) & 31, c = t >> 12;
    const float* base = skip + (size_t)c * 32768 + (oh * 2) * 512 + (ow * 2) * 8 + oz * 2;
    float m = -INFINITY;
    #pragma unroll
    for (int dh = 0; dh < 2; dh++)
        #pragma unroll
        for (int dw = 0; dw < 2; dw++)
            #pragma unroll
            for (int dz = 0; dz < 2; dz++)
                m = fmaxf(m, base[dh * 512 + dw * 8 + dz]);
    pooled[t] = m;
}

extern "C" void kernel_launch(void* const* d_in, const int* in_sizes, int n_in,
                              void* d_out, int out_size, void* d_ws, size_t ws_size,
                              hipStream_t stream) {
    const float* x      = (const float*)d_in[0];
    const float* ln1_g  = (const float*)d_in[1];
    const float* ln1_b  = (const float*)d_in[2];
    const float* qkv_w  = (const float*)d_in[3];
    const float* qkv_b  = (const float*)d_in[4];
    const float* proj_w = (const float*)d_in[5];
    const float* proj_b = (const float*)d_in[6];
    const float* rpb    = (const float*)d_in[7];
    const float* ln2_g  = (const float*)d_in[8];
    const float* ln2_b  = (const float*)d_in[9];
    const float* w1     = (const float*)d_in[10];
    const float* b1     = (const float*)d_in[11];
    const float* w2     = (const float*)d_in[12];
    const float* b2     = (const float*)d_in[13];

    const int N = NPOS;
    char* wsc = (char*)d_ws;
    bf16*  buf0 = (bf16*)wsc;                               // N*128 bf16
    bf16*  buf1 = (bf16*)(wsc + (size_t)N * 128 * 2);       // N*512 bf16
    float* buf2 = (float*)(wsc + (size_t)N * 128 * 2 + (size_t)N * 512 * 2);  // N*128 f32: x1
    char*  wts  = wsc + (size_t)N * 128 * 2 + (size_t)N * 512 * 2 + (size_t)N * 128 * 4;
    bf16* wt_qkv  = (bf16*)wts;                 // [384][128]
    bf16* wt_proj = wt_qkv  + 384 * 128;        // [128][128]
    bf16* wt_w1   = wt_proj + 128 * 128;        // [512][128]
    bf16* wt_w2   = wt_w1   + 512 * 128;        // [128][512]

    float* out_pooled = (float*)d_out;
    float* out_skip   = (float*)d_out + 524288;

    // 0. weight transposes (fp32 [K][M] -> bf16 [M][K])
    wt_transpose_kernel<<<dim3(384 / 32, 128 / 32), 256, 0, stream>>>(qkv_w, wt_qkv, 128, 384);
    wt_transpose_kernel<<<dim3(128 / 32, 128 / 32), 256, 0, stream>>>(proj_w, wt_proj, 128, 128);
    wt_transpose_kernel<<<dim3(512 / 32, 128 / 32), 256, 0, stream>>>(w1, wt_w1, 128, 512);
    wt_transpose_kernel<<<dim3(128 / 32, 512 / 32), 256, 0, stream>>>(w2, wt_w2, 512, 128);

    // 1. transpose + LN1 -> bf16
    ln1_transpose_kernel<<<N / 64, 256, 0, stream>>>(x, ln1_g, ln1_b, buf0);

    // 2. QKV GEMM: [N,128] @ [128,384] -> bf16
    gemm_mfma_kernel<0><<<dim3(N / 128, 384 / 128), 256, 0, stream>>>(
        buf0, wt_qkv, qkv_b, buf1, nullptr, nullptr, N, 128, 384);

    // 3. neighborhood attention -> bf16 (1024 blocks: 64 h x 16 w-groups)
    attn_kernel<<<1024, 256, 0, stream>>>(buf1, rpb, buf0);

    // 4. proj GEMM + residual(x^T): x1(f32) = attn_out @ proj_w + proj_b + xp
    gemm_mfma_kernel<1><<<dim3(N / 128, 1), 256, 0, stream>>>(
        buf0, wt_proj, proj_b, buf2, x, nullptr, N, 128, 128);

    // 5. LN2 -> bf16
    ln_rows_kernel<<<N / 4, 256, 0, stream>>>(buf2, ln2_g, ln2_b, buf0);

    // 6. MLP1 + gelu: [N,128] @ [128,512] -> bf16
    gemm_mfma_kernel<2><<<dim3(N / 128, 512 / 128), 256, 0, stream>>>(
        buf0, wt_w1, b1, buf1, nullptr, nullptr, N, 128, 512);

    // 7. MLP2 + bias + x1 + x -> skip (transposed fp32 write into d_out)
    gemm_mfma_kernel<3><<<dim3(N / 128, 1), 256, 0, stream>>>(
        buf1, wt_w2, b2, out_skip, x, buf2, N, 512, 128);

    // 8. maxpool -> pooled
    pool_kernel<<<(524288 + 255) / 256, 256, 0, stream>>>(out_skip, out_pooled);
}